// Round 1
// baseline (2431.931 us; speedup 1.0000x reference)
//
#include <hip/hip_runtime.h>
#include <math.h>

#define NB 4
#define NW 24
#define H 512
#define H2 1024
#define H5 2560
#define NCELL 300   // n*(n+1)/2 valid cells per batch
#define GRID 512    // 2 blocks/CU x 256 CUs; co-resident by __launch_bounds__(256,2)
#define NEED_BYTES ((size_t)72<<20)

// Private fallback workspace: allocated ONCE at library load (outside
// kernel_launch, so graph capture never sees the hipMalloc).
static float* g_buf = nullptr;
__attribute__((constructor)) static void dio_alloc_ws(){
  (void)hipMalloc((void**)&g_buf, NEED_BYTES);
}

typedef __attribute__((ext_vector_type(8))) short bf16x8;   // 8 bf16 (4 VGPRs)
typedef __attribute__((ext_vector_type(4))) float f32x4;
typedef unsigned short ushort_t;

__device__ __forceinline__ int coff(int l){ return l*NW - (l*(l-1))/2; }
__device__ __forceinline__ float sigm(float x){ return 1.f/(1.f+__expf(-x)); }
__device__ __forceinline__ float ftanh(float x){ return 1.f - 2.f/(__expf(2.f*x)+1.f); }

__device__ __forceinline__ ushort_t f2b(float x){  // fp32 -> bf16 RNE
  unsigned int u = __float_as_uint(x);
  u += 0x7FFF + ((u>>16)&1);
  return (ushort_t)(u>>16);
}
__device__ __forceinline__ float b2f(ushort_t h){
  return __uint_as_float(((unsigned int)h)<<16);
}
// split-bf16: x ~= hi + lo with effective ~2^-17 relative error
__device__ __forceinline__ void split_store(ushort_t* __restrict__ ph,
                                            ushort_t* __restrict__ pl,
                                            size_t idx, float x){
  ushort_t h = f2b(x);
  ph[idx] = h;
  pl[idx] = f2b(x - b2f(h));
}

// full-wave dot: compat(lc,rc) = U[lc].[H(rc);C(rc)] + S[lc] + S[rc]
__device__ __forceinline__ float compat_dot(const float* __restrict__ cU,
                                            const float* __restrict__ cH,
                                            const float* __restrict__ cC,
                                            const float* __restrict__ cS,
                                            int lc, int rc, int lane){
  const float4* U4  = (const float4*)(cU + (size_t)lc*H2);
  const float4* Hr4 = (const float4*)(cH + (size_t)rc*H);
  const float4* Cr4 = (const float4*)(cC + (size_t)rc*H);
  float p = 0.f;
  #pragma unroll
  for (int it=0; it<2; it++){
    float4 u = U4[lane + 64*it], h = Hr4[lane + 64*it];
    p += u.x*h.x + u.y*h.y + u.z*h.z + u.w*h.w;
  }
  #pragma unroll
  for (int it=0; it<2; it++){
    float4 u = U4[128 + lane + 64*it], c = Cr4[lane + 64*it];
    p += u.x*c.x + u.y*c.y + u.z*c.z + u.w*c.w;
  }
  #pragma unroll
  for (int off=32; off>0; off>>=1) p += __shfl_down(p, off);
  return p + cS[lc] + cS[rc];
}

__device__ __forceinline__ void mfma3(f32x4& acc, bf16x8 ah, bf16x8 al,
                                      bf16x8 bh, bf16x8 bl){
  // split product; lo*lo (~2^-34 rel) dropped
  acc = __builtin_amdgcn_mfma_f32_16x16x32_bf16(ah, bh, acc, 0,0,0);
  acc = __builtin_amdgcn_mfma_f32_16x16x32_bf16(ah, bl, acc, 0,0,0);
  acc = __builtin_amdgcn_mfma_f32_16x16x32_bf16(al, bh, acc, 0,0,0);
}

// ---- device-scope grid barrier. Monotonic counter; all GRID blocks are
// co-resident (2 blocks/CU guaranteed by launch_bounds + 67.9KB LDS < 80KB).
// Release on the RMW publishes this block's global writes (L2 writeback);
// acquire fence after the spin invalidates stale lines before we read.
__device__ __forceinline__ void gbar(unsigned* cnt, unsigned target){
  __syncthreads();
  if (threadIdx.x == 0){
    __hip_atomic_fetch_add(cnt, 1u, __ATOMIC_ACQ_REL, __HIP_MEMORY_SCOPE_AGENT);
    while (__hip_atomic_load(cnt, __ATOMIC_RELAXED, __HIP_MEMORY_SCOPE_AGENT) < target)
      __builtin_amdgcn_s_sleep(2);
    __builtin_amdgcn_fence(__ATOMIC_ACQUIRE, "agent");
  }
  __syncthreads();
}

// ---- init: leaves (grid-stride) + this block's weight j-tile -> LDS.
// Block jt<160: Wi rows [jt*16,+16); jt in [160,320): Ws; jt in [320,384):
// WbilT rows [(jt-320)*16,+16) (= Wbil columns, transposed on load).
// LDS layout (bytes), XOR-swizzled so proj's ds_read_b128 at row-stride
// 1024/2048B is only 2-way bank-conflicted (free, m136):
//   kind<2 : hi at (row<<10 | col<<1)^((row&7)<<4), lo at +16384
//   kind==2: hi at (row<<11 | col<<1)^((row&7)<<4), lo at +32768
__device__ __forceinline__ void init_phase(
    const float* __restrict__ seqt,
    const float* __restrict__ Wi, const float* __restrict__ Ws,
    const float* __restrict__ Wbil,
    float* __restrict__ cH, float* __restrict__ cC, float* __restrict__ cS,
    ushort_t* __restrict__ cHbh, ushort_t* __restrict__ cHbl,
    ushort_t* __restrict__ cCbh, ushort_t* __restrict__ cCbl,
    ushort_t* wlds)
{
  const int t = threadIdx.x;
  const int tid0 = blockIdx.x*256 + t;
  const int nthr = gridDim.x*256;
  for (int tid = tid0; tid < NB*NW*H; tid += nthr){
    const int b = tid/(NW*H); const int rr = tid%(NW*H);
    const int i = rr/H; const int dd = rr%H;
    const size_t idx = (size_t)(b*NCELL + i)*H + dd;   // coff(0)==0
    const float hv = seqt[(size_t)(b*NW+i)*H2 + dd];
    const float cv = seqt[(size_t)(b*NW+i)*H2 + H + dd];
    cH[idx]=hv; cC[idx]=cv;
    split_store(cHbh,cHbl,idx,hv);
    split_store(cCbh,cCbl,idx,cv);
    if (dd==0) cS[b*NCELL+i] = 0.f;
  }
  const int jt = blockIdx.x;
  char* wb = (char*)wlds;
  if (jt < 320){
    const float* mat = (jt<160) ? Wi : Ws;
    const int j0 = (jt%160)*16;
    for (int e = t; e < 16*512; e += 256){
      const int row = e >> 9, col = e & 511;
      const float x = mat[(size_t)(j0+row)*H + col];
      const ushort_t h = f2b(x);
      const int off = ((row<<10) + (col<<1)) ^ ((row&7)<<4);
      *(ushort_t*)(wb + off) = h;
      *(ushort_t*)(wb + 16384 + off) = f2b(x - b2f(h));
    }
  } else if (jt < 384){
    const int j0 = (jt-320)*16;
    for (int e = t; e < 16*1024; e += 256){
      const int col = e >> 4, row = e & 15;   // col=k (global), row=local j
      const float x = Wbil[(size_t)col*H2 + j0 + row];   // transpose on load
      const ushort_t h = f2b(x);
      const int off = ((row<<11) + (col<<1)) ^ ((row&7)<<4);
      *(ushort_t*)(wb + off) = h;
      *(ushort_t*)(wb + 32768 + off) = f2b(x - b2f(h));
    }
  }
}

// ---- proj for diagonal d: block jt owns one 16-col j-tile (weights in LDS),
// waves iterate m-tiles. Per (m-tile, wave): 8 independent accumulator chains
// (one per old wave-slice) summed by the SAME pairwise tree as the previous
// 8-wave LDS reduction -> bit-exact vs the multi-dispatch version.
__device__ __forceinline__ void proj_phase(
    const float* __restrict__ bi, const float* __restrict__ bs,
    const ushort_t* __restrict__ cHbh, const ushort_t* __restrict__ cHbl,
    const ushort_t* __restrict__ cCbh, const ushort_t* __restrict__ cCbl,
    float* __restrict__ cPI, float* __restrict__ cPS, float* __restrict__ cU,
    const ushort_t* wlds, int d, int P)
{
  const int jt = blockIdx.x;
  if (jt >= 384) return;
  const int t = threadIdx.x, wv = t>>6, lane = t&63;
  const int r = lane & 15, q = lane >> 4;
  int kind, j0;
  if (jt < 160){ kind=0; j0 = jt*16; }
  else if (jt < 320){ kind=1; j0 = (jt-160)*16; }
  else { kind=2; j0 = (jt-320)*16; }
  const int Mtot = NB*P, mt = (Mtot+15)>>4;
  const int swz = (r&7)<<4;
  const char* wb = (const char*)wlds;
  const int jo = j0 + r;
  float bias = 0.f;
  if (kind==0) bias = bi[jo] + ((jo>=H && jo<3*H)?1.f:0.f);   // ins_bias on [H,3H)
  else if (kind==1) bias = bs[jo];

  const f32x4 z4 = {0.f,0.f,0.f,0.f};
  for (int mtile = wv; mtile < mt; mtile += 4){
    const int m0 = mtile*16;
    const int nm = min(16, Mtot - m0);
    const int mg = m0 + (r < nm ? r : 0);
    const size_t arow = (size_t)((mg/P)*NCELL + coff(d) + mg%P)*H;
    f32x4 acc[8];
    #pragma unroll
    for (int w=0;w<8;w++) acc[w] = z4;
    if (kind < 2){
      #pragma unroll
      for (int w=0; w<8; w++){
        #pragma unroll
        for (int s=0;s<2;s++){
          const int ko = w*64 + q*8 + s*32;
          bf16x8 ah = *(const bf16x8*)(cHbh + arow + ko);
          bf16x8 al = *(const bf16x8*)(cHbl + arow + ko);
          const int bo = ((r<<10) + (ko<<1)) ^ swz;
          bf16x8 bh = *(const bf16x8*)(wb + bo);
          bf16x8 bl = *(const bf16x8*)(wb + 16384 + bo);
          mfma3(acc[w], ah, al, bh, bl);
        }
      }
    } else {
      // U: global k in [0,1024); chains 0-3 -> H chart, 4-7 -> C chart
      #pragma unroll
      for (int w=0; w<8; w++){
        const ushort_t* ah_ = (w<4 ? cHbh : cCbh) + arow;
        const ushort_t* al_ = (w<4 ? cHbl : cCbl) + arow;
        const int kg0 = w*128, ka0 = kg0 & 511;
        #pragma unroll
        for (int s=0;s<4;s++){
          const int so = s*32 + q*8;
          bf16x8 ah = *(const bf16x8*)(ah_ + ka0 + so);
          bf16x8 al = *(const bf16x8*)(al_ + ka0 + so);
          const int bo = ((r<<11) + ((kg0+so)<<1)) ^ swz;
          bf16x8 bh = *(const bf16x8*)(wb + bo);
          bf16x8 bl = *(const bf16x8*)(wb + 32768 + bo);
          mfma3(acc[w], ah, al, bh, bl);
        }
      }
    }
    f32x4 tot = ((acc[0]+acc[1])+(acc[2]+acc[3])) + ((acc[4]+acc[5])+(acc[6]+acc[7]));
    #pragma unroll
    for (int reg=0; reg<4; reg++){
      const int m = q*4 + reg;
      if (m < nm){
        const int mg2 = m0 + m;
        const size_t cell = (size_t)((mg2/P)*NCELL + coff(d) + mg2%P);
        const float v = tot[reg];
        if (kind==0)      cPI[cell*H5 + jo] = v + bias;
        else if (kind==1) cPS[cell*H5 + jo] = v + bias;
        else              cU [cell*H2 + jo] = v;
      }
    }
  }
}

// ---- combine diagonal L (same structure as the multi-dispatch k_combine3,
// block-stride over units; writer units precompute interior compat of L+1).
__device__ __forceinline__ void combine_phase(
           const float* __restrict__ cPI, const float* __restrict__ cPS,
           const float* __restrict__ cU,
           float* __restrict__ cH, float* __restrict__ cC, float* __restrict__ cS,
           ushort_t* __restrict__ cHbh, ushort_t* __restrict__ cHbl,
           ushort_t* __restrict__ cCbh, ushort_t* __restrict__ cCbl,
           const float* __restrict__ compatR, float* __restrict__ compatW,
           int L, int P){
  __shared__ float compat_s[32];
  __shared__ float wts_s[32];
  __shared__ float S_s;
  __shared__ float partH[8][32];
  __shared__ float partC[8][32];
  const int t = threadIdx.x;
  const int lane = t & 63;
  const int wave = t >> 6;
  const int nphase = NB*P*16;
  const int P1 = P-1, nterm = L-1;
  const int nwt = (P1>0 && nterm>0) ? NB*P1*nterm : 0;
  const int wblk = (nwt+3)>>2;

  for (int u = blockIdx.x; u < nphase + wblk; u += gridDim.x){
    if (u >= nphase){
      // writer: one wave per (cell of diag L+1, split k in [1,L-1])
      const int tid = (u-nphase)*4 + wave;
      if (tid < nwt){
        const int cell1 = tid / nterm;
        const int k = 1 + tid % nterm;
        const int b = cell1 / P1, left = cell1 % P1;
        const int lc = b*NCELL + coff(k) + left;
        const int rc = b*NCELL + coff(L-k) + left+k+1;
        float v = compat_dot(cU, cH, cC, cS, lc, rc, lane);
        if (lane==0) compatW[(b*NW + left)*NW + k] = v;
      }
      continue;   // uniform per block (branch depends on u only)
    }
    const int cellid = u >> 4;
    const int dg = u & 15;            // dim-group: dims [dg*32, dg*32+32)
    const int b = cellid / P;
    const int left = cellid % P;
    __syncthreads();                  // guard LDS reuse across unit iterations
    // phase 1: boundary compat inline; interior from precomputed buffer
    if (wave == 0){
      const int lc = b*NCELL + left;                       // (left,0) leaf
      const int rc = b*NCELL + coff(L-1) + left+1;
      float v = compat_dot(cU, cH, cC, cS, lc, rc, lane);
      if (lane==0) compat_s[0] = v;
    } else if (wave == 1 && L >= 2){
      const int lc = b*NCELL + coff(L-1) + left;
      const int rc = b*NCELL + left+L;                     // (left+L,0) leaf
      float v = compat_dot(cU, cH, cC, cS, lc, rc, lane);
      if (lane==0) compat_s[L-1] = v;
    }
    if (t >= 1 && t <= L-2) compat_s[t] = compatR[(b*NW + left)*NW + t];
    __syncthreads();
    // phase 2: softmax over k (L<=23, serial on thread 0)
    if (t==0){
      float mx = -1e30f;
      for (int k=0;k<L;k++) mx = fmaxf(mx, compat_s[k]);
      float den = 0.f;
      for (int k=0;k<L;k++){ float e = __expf(compat_s[k]-mx); wts_s[k]=e; den+=e; }
      float inv = 1.f/den, S = 0.f;
      for (int k=0;k<L;k++){ wts_s[k]*=inv; S += wts_s[k]*compat_s[k]; }
      S_s = S;
    }
    __syncthreads();
    // phase 3: thread owns 1 dim; t>>5 selects k-residue (8-way split)
    const int dloc = t & 31;
    const int dim = dg*32 + dloc;
    const int kpar = t >> 5;
    float aH = 0.f, aC = 0.f;
    for (int k=kpar; k<L; k+=8){
      float wk = wts_s[k];
      const int lc = b*NCELL + coff(k) + left;
      const int rc = b*NCELL + coff(L-1-k) + left+k+1;
      const float* PI = cPI + (size_t)lc*H5;
      const float* PS = cPS + (size_t)rc*H5;
      float p0 = PI[dim]     + PS[dim];
      float p1 = PI[H+dim]   + PS[H+dim];
      float p2 = PI[2*H+dim] + PS[2*H+dim];
      float p3 = PI[3*H+dim] + PS[3*H+dim];
      float p4 = PI[4*H+dim] + PS[4*H+dim];
      float lcv = cC[(size_t)lc*H + dim];
      float rcv = cC[(size_t)rc*H + dim];
      float mem = sigm(p1)*lcv + sigm(p2)*rcv + sigm(p0)*ftanh(p3);
      float h = sigm(p4)*ftanh(mem);
      aH += wk*h; aC += wk*mem;
    }
    if (kpar > 0){ partH[kpar][dloc]=aH; partC[kpar][dloc]=aC; }
    __syncthreads();
    if (kpar == 0){
      #pragma unroll
      for (int qq=1;qq<8;qq++){ aH += partH[qq][dloc]; aC += partC[qq][dloc]; }
      const size_t nc = (size_t)(b*NCELL + coff(L) + left);
      cH[nc*H + dim] = aH;
      cC[nc*H + dim] = aC;
      split_store(cHbh,cHbl, nc*H + dim, aH);
      split_store(cCbh,cCbl, nc*H + dim, aC);
      if (t==0 && dg==0) cS[nc] = S_s;
    }
  }
}

// ---- the whole inside pass as ONE persistent kernel with grid barriers.
__global__ void __launch_bounds__(256, 2)
k_persist(const float* __restrict__ seqt,
          const float* __restrict__ Wi, const float* __restrict__ bi,
          const float* __restrict__ Ws, const float* __restrict__ bs,
          const float* __restrict__ Wbil,
          float* __restrict__ cH, float* __restrict__ cC, float* __restrict__ cS,
          float* __restrict__ cPI, float* __restrict__ cPS, float* __restrict__ cU,
          float* __restrict__ compatA, float* __restrict__ compatB,
          ushort_t* __restrict__ cHbh, ushort_t* __restrict__ cHbl,
          ushort_t* __restrict__ cCbh, ushort_t* __restrict__ cCbl,
          float* __restrict__ out, unsigned* __restrict__ barcnt)
{
  __shared__ __attribute__((aligned(16))) ushort_t wlds[32768];  // 64KB weight tile
  unsigned gen = 0;

  init_phase(seqt, Wi, Ws, Wbil, cH, cC, cS, cHbh, cHbl, cCbh, cCbl, wlds);
  gbar(barcnt, (++gen)*gridDim.x);

  proj_phase(bi, bs, cHbh, cHbl, cCbh, cCbl, cPI, cPS, cU, wlds, 0, NW);
  gbar(barcnt, (++gen)*gridDim.x);

  for (int L=1; L<NW; L++){
    const int P = NW - L;
    const float* bufR = (L&1) ? compatA : compatB;
    float* bufW = (L&1) ? compatB : compatA;
    combine_phase(cPI, cPS, cU, cH, cC, cS, cHbh, cHbl, cCbh, cCbl,
                  bufR, bufW, L, P);
    gbar(barcnt, (++gen)*gridDim.x);
    if (L < NW-1){
      proj_phase(bi, bs, cHbh, cHbl, cCbh, cCbl, cPI, cPS, cU, wlds, L, P);
      gbar(barcnt, (++gen)*gridDim.x);
    }
  }
  // root output: concat(H, C) of cell (0, n-1)
  const int tid = blockIdx.x*256 + threadIdx.x;
  if (tid < NB*H2){
    const int b = tid>>10, dd = tid&1023;
    const int cell = b*NCELL + 299;   // coff(23)+0
    out[tid] = (dd<H) ? cH[(size_t)cell*H + dd] : cC[(size_t)cell*H + (dd-H)];
  }
}

extern "C" void kernel_launch(void* const* d_in, const int* in_sizes, int n_in,
                              void* d_out, int out_size, void* d_ws, size_t ws_size,
                              hipStream_t stream){
  const float* seqt = (const float*)d_in[0];
  const float* Wi   = (const float*)d_in[1];
  const float* bi   = (const float*)d_in[2];
  const float* Ws   = (const float*)d_in[3];
  const float* bs   = (const float*)d_in[4];
  const float* Wbil = (const float*)d_in[5];
  float* out = (float*)d_out;

  float* p = (ws_size >= NEED_BYTES && g_buf == nullptr) ? (float*)d_ws : g_buf;
  float* cH  = p; p += (size_t)NB*NCELL*H;
  float* cC  = p; p += (size_t)NB*NCELL*H;
  float* cS  = p; p += (size_t)NB*NCELL;
  float* cPI = p; p += (size_t)NB*NCELL*H5;
  float* cPS = p; p += (size_t)NB*NCELL*H5;
  float* cU  = p; p += (size_t)NB*NCELL*H2;
  float* compatA = p; p += (size_t)NB*NW*NW;
  float* compatB = p; p += (size_t)NB*NW*NW;
  ushort_t* u = (ushort_t*)p;
  ushort_t* cHbh = u; u += (size_t)NB*NCELL*H;
  ushort_t* cHbl = u; u += (size_t)NB*NCELL*H;
  ushort_t* cCbh = u; u += (size_t)NB*NCELL*H;
  ushort_t* cCbl = u; u += (size_t)NB*NCELL*H;
  unsigned* barcnt = (unsigned*)u;     // 4B-aligned (even ushort counts)

  (void)hipMemsetAsync(barcnt, 0, 64, stream);
  k_persist<<<GRID, 256, 0, stream>>>(seqt, Wi, bi, Ws, bs, Wbil,
      cH, cC, cS, cPI, cPS, cU, compatA, compatB,
      cHbh, cHbl, cCbh, cCbl, out, barcnt);
}

// Round 2
// 584.090 us; speedup vs baseline: 4.1636x; 4.1636x over previous
//
#include <hip/hip_runtime.h>
#include <math.h>

#define NB 4
#define NW 24
#define H 512
#define H2 1024
#define H5 2560
#define NCELL 300   // n*(n+1)/2 valid cells per batch
#define NEED_BYTES ((size_t)72<<20)

// Private fallback workspace: allocated ONCE at library load (outside
// kernel_launch, so graph capture never sees the hipMalloc).
static float* g_buf = nullptr;
__attribute__((constructor)) static void dio_alloc_ws(){
  (void)hipMalloc((void**)&g_buf, NEED_BYTES);
}

typedef __attribute__((ext_vector_type(8))) short bf16x8;   // 8 bf16 (4 VGPRs)
typedef __attribute__((ext_vector_type(4))) float f32x4;
typedef unsigned short ushort_t;

__device__ __forceinline__ int coff(int l){ return l*NW - (l*(l-1))/2; }
__device__ __forceinline__ float sigm(float x){ return 1.f/(1.f+__expf(-x)); }
__device__ __forceinline__ float ftanh(float x){ return 1.f - 2.f/(__expf(2.f*x)+1.f); }

__device__ __forceinline__ ushort_t f2b(float x){  // fp32 -> bf16 RNE
  unsigned int u = __float_as_uint(x);
  u += 0x7FFF + ((u>>16)&1);
  return (ushort_t)(u>>16);
}
__device__ __forceinline__ float b2f(ushort_t h){
  return __uint_as_float(((unsigned int)h)<<16);
}
// split-bf16: x ~= hi + lo with effective ~2^-17 relative error
__device__ __forceinline__ void split_store(ushort_t* __restrict__ ph,
                                            ushort_t* __restrict__ pl,
                                            size_t idx, float x){
  ushort_t h = f2b(x);
  ph[idx] = h;
  pl[idx] = f2b(x - b2f(h));
}

// full-wave dot: compat(lc,rc) = U[lc].[H(rc);C(rc)] + S[lc] + S[rc]
__device__ __forceinline__ float compat_dot(const float* __restrict__ cU,
                                            const float* __restrict__ cH,
                                            const float* __restrict__ cC,
                                            const float* __restrict__ cS,
                                            int lc, int rc, int lane){
  const float4* U4  = (const float4*)(cU + (size_t)lc*H2);
  const float4* Hr4 = (const float4*)(cH + (size_t)rc*H);
  const float4* Cr4 = (const float4*)(cC + (size_t)rc*H);
  float p = 0.f;
  #pragma unroll
  for (int it=0; it<2; it++){
    float4 u = U4[lane + 64*it], h = Hr4[lane + 64*it];
    p += u.x*h.x + u.y*h.y + u.z*h.z + u.w*h.w;
  }
  #pragma unroll
  for (int it=0; it<2; it++){
    float4 u = U4[128 + lane + 64*it], c = Cr4[lane + 64*it];
    p += u.x*c.x + u.y*c.y + u.z*c.z + u.w*c.w;
  }
  #pragma unroll
  for (int off=32; off>0; off>>=1) p += __shfl_down(p, off);
  return p + cS[lc] + cS[rc];
}

// ---- merged init: split Wi/Ws, transpose+split Wbil, leaves
__global__ void k_init(const float* __restrict__ seqt,
                       const float* __restrict__ Wi, const float* __restrict__ Ws,
                       const float* __restrict__ Wbil,
                       ushort_t* __restrict__ WiBh, ushort_t* __restrict__ WiBl,
                       ushort_t* __restrict__ WsBh, ushort_t* __restrict__ WsBl,
                       ushort_t* __restrict__ WbilTh, ushort_t* __restrict__ WbilTl,
                       float* __restrict__ cH, float* __restrict__ cC, float* __restrict__ cS,
                       ushort_t* __restrict__ cHbh, ushort_t* __restrict__ cHbl,
                       ushort_t* __restrict__ cCbh, ushort_t* __restrict__ cCbl){
  const int blk = blockIdx.x, t = threadIdx.x;
  if (blk < 10240){                       // Wi/Ws split (2*H5*H elems exactly)
    int i = blk*256 + t;
    const int n = H5*H;
    if (i < n) split_store(WiBh, WiBl, i, Wi[i]);
    else       split_store(WsBh, WsBl, i-n, Ws[i-n]);
  } else if (blk < 11264){                // Wbil transpose+split (1024 tiles)
    __shared__ float tile[32][33];
    int tb = blk - 10240;
    int tr = (tb>>5)*32, tc = (tb&31)*32;
    int tx = t & 31, ty = t >> 5;         // 32 x 8
    #pragma unroll
    for (int i=0;i<32;i+=8)
      tile[ty+i][tx] = Wbil[(size_t)(tr+ty+i)*H2 + tc+tx];
    __syncthreads();
    #pragma unroll
    for (int i=0;i<32;i+=8)
      split_store(WbilTh, WbilTl, (size_t)(tc+ty+i)*H2 + tr+tx, tile[tx][ty+i]);
  } else {                                // leaves (192 blocks)
    int tid = (blk-11264)*256 + t;
    if (tid < NB*NW*H){
      int b = tid/(NW*H); int r = tid%(NW*H); int i = r/H; int d = r%H;
      size_t idx = (size_t)(b*NCELL + i)*H + d;     // coff(0)==0
      float hv = seqt[(size_t)(b*NW+i)*H2 + d];
      float cv = seqt[(size_t)(b*NW+i)*H2 + H + d];
      cH[idx]=hv; cC[idx]=cv;
      split_store(cHbh,cHbl,idx,hv);
      split_store(cCbh,cCbl,idx,cv);
      if (d==0) cS[b*NCELL+i] = 0.f;
    }
  }
}

__device__ __forceinline__ void mfma3(f32x4& acc, bf16x8 ah, bf16x8 al,
                                      bf16x8 bh, bf16x8 bl){
  // split product; lo*lo (~2^-34 rel) dropped
  acc = __builtin_amdgcn_mfma_f32_16x16x32_bf16(ah, bh, acc, 0,0,0);
  acc = __builtin_amdgcn_mfma_f32_16x16x32_bf16(ah, bl, acc, 0,0,0);
  acc = __builtin_amdgcn_mfma_f32_16x16x32_bf16(al, bh, acc, 0,0,0);
}

// ---- MFMA projections, one block per j-tile, weights LDS-resident.
// grid.x = 384 (0-159: PI, 160-319: PS, 320-383: U), 512 threads.
// Each block stages its 16-col split-weight tile into LDS ONCE (reg-staged,
// XOR-swizzled (row&7)<<4 so ds_read_b128 at 1024/2048B row stride is only
// 2-way bank-aliased = free), then wave PAIRS sweep all m-tiles: even wave
// computes K-chains 0-3 (subtree (0+1)+(2+3)), odd wave chains 4-7; the
// final sA+sB matches the old 8-wave LDS tree exactly -> bit-exact.
__global__ void __launch_bounds__(512)
k_proj2(const ushort_t* __restrict__ WiBh, const ushort_t* __restrict__ WiBl,
        const ushort_t* __restrict__ WsBh, const ushort_t* __restrict__ WsBl,
        const ushort_t* __restrict__ WbilTh, const ushort_t* __restrict__ WbilTl,
        const float* __restrict__ bi, const float* __restrict__ bs,
        const ushort_t* __restrict__ cHbh, const ushort_t* __restrict__ cHbl,
        const ushort_t* __restrict__ cCbh, const ushort_t* __restrict__ cCbl,
        float* __restrict__ cPI, float* __restrict__ cPS, float* __restrict__ cU,
        int d, int P)
{
  __shared__ __attribute__((aligned(16))) ushort_t wlds[32768];  // 64 KB
  __shared__ f32x4 red[8][64];                                   // 8 KB
  const int t = threadIdx.x, wv = t>>6, lane = t&63;
  const int r = lane & 15;   // A row (m) / B row (j) / D col
  const int q = lane >> 4;   // quad: k = q*8 + i
  const int jt = blockIdx.x;

  int kind, j0;
  if (jt < 160){ kind=0; j0 = jt*16; }
  else if (jt < 320){ kind=1; j0 = (jt-160)*16; }
  else { kind=2; j0 = (jt-320)*16; }

  // ---- stage weights into LDS (once per dispatch)
  char* wb = (char*)wlds;
  if (kind < 2){
    const ushort_t* srcH = (kind==0 ? WiBh : WsBh) + (size_t)j0*H;
    const ushort_t* srcL = (kind==0 ? WiBl : WsBl) + (size_t)j0*H;
    #pragma unroll
    for (int e = t; e < 1024; e += 512){          // 16B chunks: 16 rows x 64
      const int row = e >> 6, c0 = (e & 63) << 3;
      bf16x8 vh = *(const bf16x8*)(srcH + (size_t)row*H + c0);
      bf16x8 vl = *(const bf16x8*)(srcL + (size_t)row*H + c0);
      const int off = ((row<<10) + (c0<<1)) ^ ((row&7)<<4);
      *(bf16x8*)(wb + off) = vh;
      *(bf16x8*)(wb + 16384 + off) = vl;
    }
  } else {
    const ushort_t* srcH = WbilTh + (size_t)j0*H2;
    const ushort_t* srcL = WbilTl + (size_t)j0*H2;
    #pragma unroll
    for (int e = t; e < 2048; e += 512){          // 16 rows x 128 chunks
      const int row = e >> 7, c0 = (e & 127) << 3;
      bf16x8 vh = *(const bf16x8*)(srcH + (size_t)row*H2 + c0);
      bf16x8 vl = *(const bf16x8*)(srcL + (size_t)row*H2 + c0);
      const int off = ((row<<11) + (c0<<1)) ^ ((row&7)<<4);
      *(bf16x8*)(wb + off) = vh;
      *(bf16x8*)(wb + 32768 + off) = vl;
    }
  }
  __syncthreads();

  const int Mtot = NB*P, mt = (Mtot+15)>>4;
  const int swz = (r&7)<<4;
  const int jo = j0 + r;
  float bias = 0.f;
  if (kind==0) bias = bi[jo] + ((jo>=H && jo<3*H)?1.f:0.f);   // ins_bias on [H,3H)
  else if (kind==1) bias = bs[jo];

  const f32x4 z4 = {0.f,0.f,0.f,0.f};
  const int units = 2*mt;                 // (m-tile, K-half) pairs
  const int rounds = (units + 7) >> 3;
  for (int rd = 0; rd < rounds; rd++){
    const int u = rd*8 + wv;
    const int half = u & 1;               // wv parity (rd*8 even)
    const int mtile = u >> 1;
    f32x4 sA = z4;
    int m0 = 0, nm = 0;
    if (u < units){
      m0 = mtile*16;
      nm = min(16, Mtot - m0);
      const int mg = m0 + (r < nm ? r : 0);
      const size_t arow = (size_t)((mg/P)*NCELL + coff(d) + mg%P)*H;
      f32x4 acc[4];
      #pragma unroll
      for (int wi=0;wi<4;wi++) acc[wi] = z4;
      if (kind < 2){
        #pragma unroll
        for (int wi=0; wi<4; wi++){
          const int w = half*4 + wi;      // chain id 0..7
          #pragma unroll
          for (int s=0;s<2;s++){
            const int ko = w*64 + q*8 + s*32;
            bf16x8 ah = *(const bf16x8*)(cHbh + arow + ko);
            bf16x8 al = *(const bf16x8*)(cHbl + arow + ko);
            const int bo = ((r<<10) + (ko<<1)) ^ swz;
            bf16x8 bh = *(const bf16x8*)(wb + bo);
            bf16x8 bl = *(const bf16x8*)(wb + 16384 + bo);
            mfma3(acc[wi], ah, al, bh, bl);
          }
        }
      } else {
        // U: chains 0-3 -> H chart, 4-7 -> C chart; global k = w*128 + ...
        const ushort_t* ah_ = (half==0 ? cHbh : cCbh) + arow;
        const ushort_t* al_ = (half==0 ? cHbl : cCbl) + arow;
        #pragma unroll
        for (int wi=0; wi<4; wi++){
          const int w = half*4 + wi;
          const int kg0 = w*128, ka0 = kg0 & 511;
          #pragma unroll
          for (int s=0;s<4;s++){
            const int so = s*32 + q*8;
            bf16x8 ah = *(const bf16x8*)(ah_ + ka0 + so);
            bf16x8 al = *(const bf16x8*)(al_ + ka0 + so);
            const int bo = ((r<<11) + ((kg0+so)<<1)) ^ swz;
            bf16x8 bh = *(const bf16x8*)(wb + bo);
            bf16x8 bl = *(const bf16x8*)(wb + 32768 + bo);
            mfma3(acc[wi], ah, al, bh, bl);
          }
        }
      }
      sA = (acc[0]+acc[1]) + (acc[2]+acc[3]);   // half-subtree, fixed order
    }
    red[wv][lane] = sA;
    __syncthreads();
    if (half==0 && u < units){
      f32x4 tot = red[wv][lane] + red[wv|1][lane];   // ((0+1)+(2+3))+((4+5)+(6+7))
      #pragma unroll
      for (int reg=0; reg<4; reg++){
        const int m = q*4 + reg;
        if (m < nm){
          const int mg2 = m0 + m;
          const size_t cell = (size_t)((mg2/P)*NCELL + coff(d) + mg2%P);
          const float v = tot[reg];
          if (kind==0)      cPI[cell*H5 + jo] = v + bias;
          else if (kind==1) cPS[cell*H5 + jo] = v + bias;
          else              cU [cell*H2 + jo] = v;
        }
      }
    }
    __syncthreads();   // red reused next round
  }
}

// ---- combine diagonal L. Phase 1 hoisted: compat terms k in [1,L-2] were
// precomputed by the PREVIOUS combine dispatch's writer blocks (they touch
// only diag <= L-2 data, final then); only boundary terms k=0 and k=L-1
// (touching diag L-1) are computed inline. This dispatch's extra blocks
// precompute compat terms k in [1,L-1] for diag L+1 into the ping-pong
// write buffer (reads diag <= L-1 only -> no race with phase writes to
// diag L). Phase 3: 32 dims x 8-way k-split.
// grid.x = NB*P*16 phase blocks + ceil(NB*(P-1)*(L-1)/4) writer blocks.
__global__ void __launch_bounds__(256)
k_combine3(const float* __restrict__ cPI, const float* __restrict__ cPS,
           const float* __restrict__ cU,
           float* __restrict__ cH, float* __restrict__ cC, float* __restrict__ cS,
           ushort_t* __restrict__ cHbh, ushort_t* __restrict__ cHbl,
           ushort_t* __restrict__ cCbh, ushort_t* __restrict__ cCbl,
           const float* __restrict__ compatR, float* __restrict__ compatW,
           int L, int P){
  const int t = threadIdx.x;
  const int lane = t & 63;
  const int wave = t >> 6;
  const int nphase = NB*P*16;
  const int blk = blockIdx.x;

  if (blk >= nphase){
    // writer: one wave per (cell of diag L+1, split k in [1,L-1])
    const int P1 = P-1;
    const int nterm = L-1;
    int tid = (blk-nphase)*4 + wave;
    if (P1 > 0 && nterm > 0 && tid < NB*P1*nterm){
      int cell1 = tid / nterm;
      int k = 1 + tid % nterm;
      int b = cell1 / P1, left = cell1 % P1;
      // diag L+1 span (left): lcell=(left,k), rcell=(left+k+1, L-k)
      int lc = b*NCELL + coff(k) + left;
      int rc = b*NCELL + coff(L-k) + left+k+1;
      float v = compat_dot(cU, cH, cC, cS, lc, rc, lane);
      if (lane==0) compatW[(b*NW + left)*NW + k] = v;
    }
    return;
  }

  const int cellid = blk >> 4;
  const int dg = blk & 15;            // dim-group: dims [dg*32, dg*32+32)
  const int b = cellid / P;
  const int left = cellid % P;
  __shared__ float compat_s[32];
  __shared__ float wts_s[32];
  __shared__ float S_s;
  __shared__ float partH[8][32];
  __shared__ float partC[8][32];

  // phase 1: boundary terms inline (k=0 by wave 0, k=L-1 by wave 1);
  // interior terms from the precomputed buffer.
  if (wave == 0){
    int lc = b*NCELL + left;                       // (left,0) leaf
    int rc = b*NCELL + coff(L-1) + left+1;
    float v = compat_dot(cU, cH, cC, cS, lc, rc, lane);
    if (lane==0) compat_s[0] = v;
  } else if (wave == 1 && L >= 2){
    int lc = b*NCELL + coff(L-1) + left;
    int rc = b*NCELL + left+L;                     // (left+L,0) leaf
    float v = compat_dot(cU, cH, cC, cS, lc, rc, lane);
    if (lane==0) compat_s[L-1] = v;
  }
  if (t >= 1 && t <= L-2) compat_s[t] = compatR[(b*NW + left)*NW + t];
  __syncthreads();
  // phase 2: softmax over k (L<=23, serial on thread 0)
  if (t==0){
    float mx = -1e30f;
    for (int k=0;k<L;k++) mx = fmaxf(mx, compat_s[k]);
    float den = 0.f;
    for (int k=0;k<L;k++){ float e = __expf(compat_s[k]-mx); wts_s[k]=e; den+=e; }
    float inv = 1.f/den, S = 0.f;
    for (int k=0;k<L;k++){ wts_s[k]*=inv; S += wts_s[k]*compat_s[k]; }
    S_s = S;
  }
  __syncthreads();
  // phase 3: thread owns 1 dim; t>>5 selects k-residue (8-way split)
  const int dloc = t & 31;
  const int dim = dg*32 + dloc;
  const int kpar = t >> 5;
  float aH = 0.f, aC = 0.f;
  for (int k=kpar; k<L; k+=8){
    float wk = wts_s[k];
    int lc = b*NCELL + coff(k) + left;
    int rc = b*NCELL + coff(L-1-k) + left+k+1;
    const float* PI = cPI + (size_t)lc*H5;
    const float* PS = cPS + (size_t)rc*H5;
    float p0 = PI[dim]     + PS[dim];
    float p1 = PI[H+dim]   + PS[H+dim];
    float p2 = PI[2*H+dim] + PS[2*H+dim];
    float p3 = PI[3*H+dim] + PS[3*H+dim];
    float p4 = PI[4*H+dim] + PS[4*H+dim];
    float lcv = cC[(size_t)lc*H + dim];
    float rcv = cC[(size_t)rc*H + dim];
    float mem = sigm(p1)*lcv + sigm(p2)*rcv + sigm(p0)*ftanh(p3);
    float h = sigm(p4)*ftanh(mem);
    aH += wk*h; aC += wk*mem;
  }
  if (kpar > 0){ partH[kpar][dloc]=aH; partC[kpar][dloc]=aC; }
  __syncthreads();
  if (kpar == 0){
    #pragma unroll
    for (int q=1;q<8;q++){ aH += partH[q][dloc]; aC += partC[q][dloc]; }
    size_t nc = (size_t)(b*NCELL + coff(L) + left);
    cH[nc*H + dim] = aH;
    cC[nc*H + dim] = aC;
    split_store(cHbh,cHbl, nc*H + dim, aH);
    split_store(cCbh,cCbl, nc*H + dim, aC);
    if (t==0 && dg==0) cS[nc] = S_s;
  }
}

// ---- root output: concat(H, C) of cell (0, n-1)
__global__ void k_out(const float* __restrict__ cH, const float* __restrict__ cC,
                      float* __restrict__ out){
  int tid = blockIdx.x*256+threadIdx.x;
  if (tid >= NB*H2) return;
  int b = tid>>10, d = tid&1023;
  int cell = b*NCELL + 299;   // coff(23)+0
  out[tid] = (d<H) ? cH[(size_t)cell*H + d] : cC[(size_t)cell*H + (d-H)];
}

extern "C" void kernel_launch(void* const* d_in, const int* in_sizes, int n_in,
                              void* d_out, int out_size, void* d_ws, size_t ws_size,
                              hipStream_t stream){
  const float* seqt = (const float*)d_in[0];
  const float* Wi   = (const float*)d_in[1];
  const float* bi   = (const float*)d_in[2];
  const float* Ws   = (const float*)d_in[3];
  const float* bs   = (const float*)d_in[4];
  const float* Wbil = (const float*)d_in[5];
  float* out = (float*)d_out;

  float* p = (ws_size >= NEED_BYTES && g_buf == nullptr) ? (float*)d_ws : g_buf;
  float* cH  = p; p += (size_t)NB*NCELL*H;
  float* cC  = p; p += (size_t)NB*NCELL*H;
  float* cS  = p; p += (size_t)NB*NCELL;
  float* cPI = p; p += (size_t)NB*NCELL*H5;
  float* cPS = p; p += (size_t)NB*NCELL*H5;
  float* cU  = p; p += (size_t)NB*NCELL*H2;
  float* compatA = p; p += (size_t)NB*NW*NW;
  float* compatB = p; p += (size_t)NB*NW*NW;
  ushort_t* u = (ushort_t*)p;
  ushort_t* WiBh   = u; u += (size_t)H5*H;
  ushort_t* WiBl   = u; u += (size_t)H5*H;
  ushort_t* WsBh   = u; u += (size_t)H5*H;
  ushort_t* WsBl   = u; u += (size_t)H5*H;
  ushort_t* WbilTh = u; u += (size_t)H2*H2;
  ushort_t* WbilTl = u; u += (size_t)H2*H2;
  ushort_t* cHbh   = u; u += (size_t)NB*NCELL*H;
  ushort_t* cHbl   = u; u += (size_t)NB*NCELL*H;
  ushort_t* cCbh   = u; u += (size_t)NB*NCELL*H;
  ushort_t* cCbl   = u; u += (size_t)NB*NCELL*H;

  k_init<<<11456, 256, 0, stream>>>(seqt, Wi, Ws, Wbil,
      WiBh, WiBl, WsBh, WsBl, WbilTh, WbilTl,
      cH, cC, cS, cHbh, cHbl, cCbh, cCbl);

  k_proj2<<<384, 512, 0, stream>>>(
      WiBh, WiBl, WsBh, WsBl, WbilTh, WbilTl, bi, bs,
      cHbh, cHbl, cCbh, cCbl, cPI, cPS, cU, 0, NW);
  for (int L=1; L<NW; L++){
    int P = NW - L;
    // writer blocks precompute compat interior terms for diagonal L+1
    int P1 = P-1, nterm = L-1;
    int wblk = (P1>0 && nterm>0) ? (NB*P1*nterm + 3)/4 : 0;
    float* bufR = (L&1) ? compatA : compatB;
    float* bufW = (L&1) ? compatB : compatA;
    k_combine3<<<NB*P*16 + wblk, 256, 0, stream>>>(
        cPI, cPS, cU, cH, cC, cS, cHbh, cHbl, cCbh, cCbl,
        bufR, bufW, L, P);
    if (L < NW-1)
      k_proj2<<<384, 512, 0, stream>>>(
          WiBh, WiBl, WsBh, WsBl, WbilTh, WbilTl, bi, bs,
          cHbh, cHbl, cCbh, cCbl, cPI, cPS, cU, L, P);
  }
  k_out<<<16, 256, 0, stream>>>(cH, cC, out);
}